// Round 1
// baseline (50.378 us; speedup 1.0000x reference)
//
#include <hip/hip_runtime.h>
#include <math.h>

#define NG 512
#define NV 76800
#define FD 32

__global__ __launch_bounds__(256) void voxelize_kernel(
    const float* __restrict__ means, const float* __restrict__ opac,
    const float* __restrict__ cov, const float* __restrict__ feats,
    float* __restrict__ out)
{
    // Per-gaussian derived data, recomputed per block (trivial cost), LDS broadcast reads.
    __shared__ float g[NG][12];
    const int tid = threadIdx.x;

    for (int n = tid; n < NG; n += 256) {
        const float a = cov[n*9+0], b = cov[n*9+1], c = cov[n*9+2];
        const float d = cov[n*9+4], e = cov[n*9+5], f = cov[n*9+8];
        const float sx = sqrtf(a), sy = sqrtf(d), sz = sqrtf(f);
        const float mx = means[n*3+0], my = means[n*3+1], mz = means[n*3+2];
        const float op = opac[n];
        const bool keep =
            (mx + 3.f*sx > -20.f) && (my + 3.f*sy > -20.f) && (mz + 3.f*sz > -2.f) &&
            (mx - 3.f*sx <  20.f) && (my - 3.f*sy <  20.f) && (mz - 3.f*sz <  4.4f) &&
            (op > 1e-4f);
        const float smax = fmaxf(sx, fmaxf(sy, sz));
        const float r2 = keep ? 9.f * smax * smax : -1.f;  // r2=-1 culls: d2 < -1 never true
        // symmetric 3x3 inverse via adjugate
        const float det = a*(d*f - e*e) - b*(b*f - c*e) + c*(b*e - c*d);
        const float id = 1.f / det;
        g[n][0]  = mx; g[n][1] = my; g[n][2] = mz;
        g[n][3]  = op;
        g[n][4]  = (d*f - e*e) * id;   // i00
        g[n][5]  = (c*e - b*f) * id;   // i01
        g[n][6]  = (b*e - c*d) * id;   // i02
        g[n][7]  = (a*f - c*c) * id;   // i11
        g[n][8]  = (b*c - a*e) * id;   // i12
        g[n][9]  = (a*d - b*b) * id;   // i22
        g[n][10] = r2;
        g[n][11] = 0.f;
    }
    __syncthreads();

    const int v  = blockIdx.x * 256 + tid;
    const int iz = v % 12;
    const int ixy = v / 12;
    const int iy = ixy % 80;
    const int ix = ixy / 80;
    const float x = (ix + 0.5f) * 0.5f - 20.f;
    const float y = (iy + 0.5f) * 0.5f - 20.f;
    const float z = (iz + 0.5f) * 0.5f -  2.f;

    float dens = 0.f;
    float4 acc[8];
    #pragma unroll
    for (int j = 0; j < 8; ++j) acc[j] = make_float4(0.f, 0.f, 0.f, 0.f);

    for (int n = 0; n < NG; ++n) {
        const float* gn = g[n];
        const float dx = gn[0] - x, dy = gn[1] - y, dz = gn[2] - z;
        const float d2 = dx*dx + dy*dy + dz*dz;
        if (d2 < gn[10]) {
            const float maha = gn[4]*dx*dx + gn[7]*dy*dy + gn[9]*dz*dz
                             + 2.f*(gn[5]*dx*dy + gn[6]*dx*dz + gn[8]*dy*dz);
            const float w = gn[3] * __expf(-0.5f * maha);
            dens += w;
            const float4* fp = (const float4*)(feats + n*FD);
            #pragma unroll
            for (int j = 0; j < 8; ++j) {
                const float4 f4 = fp[j];
                acc[j].x += w * f4.x; acc[j].y += w * f4.y;
                acc[j].z += w * f4.z; acc[j].w += w * f4.w;
            }
        }
    }

    out[v] = dens;
    const float inv = 1.f / fmaxf(dens, 1e-6f);
    float4* fo = (float4*)(out + NV + (size_t)v * FD);
    #pragma unroll
    for (int j = 0; j < 8; ++j) {
        float4 r;
        r.x = acc[j].x * inv; r.y = acc[j].y * inv;
        r.z = acc[j].z * inv; r.w = acc[j].w * inv;
        fo[j] = r;
    }
}

extern "C" void kernel_launch(void* const* d_in, const int* in_sizes, int n_in,
                              void* d_out, int out_size, void* d_ws, size_t ws_size,
                              hipStream_t stream) {
    const float* means = (const float*)d_in[0];
    const float* opac  = (const float*)d_in[1];
    const float* cov   = (const float*)d_in[2];
    const float* feats = (const float*)d_in[3];
    float* out = (float*)d_out;
    voxelize_kernel<<<NV / 256, 256, 0, stream>>>(means, opac, cov, feats, out);
}

// Round 2
// 13.746 us; speedup vs baseline: 3.6649x; 3.6649x over previous
//
#include <hip/hip_runtime.h>
#include <math.h>

#define NG 512
#define NV 76800
#define FD 32
// grid 80x80x12 voxels, tiles 8x8x4 -> 10x10x3 = 300 tiles

__global__ __launch_bounds__(256) void voxelize_kernel(
    const float* __restrict__ means, const float* __restrict__ opac,
    const float* __restrict__ cov, const float* __restrict__ feats,
    float* __restrict__ out)
{
    // per-wave compacted gaussian lists: [wave][slot][{pos+r2, inv0, inv1}]
    __shared__ float4 gd[4][128][3];
    __shared__ int cnt[4];

    const int tid  = threadIdx.x;
    const int wv   = tid >> 6;
    const int lane = tid & 63;

    // tile coords
    const int b   = blockIdx.x;
    const int tiz = b % 3;
    const int tiy = (b / 3) % 10;
    const int tix = b / 30;

    // tile voxel-center AABB (world units)
    const float xlo = (tix * 8 + 0.5f) * 0.5f - 20.f, xhi = xlo + 3.5f;
    const float ylo = (tiy * 8 + 0.5f) * 0.5f - 20.f, yhi = ylo + 3.5f;
    const float zlo = (tiz * 4 + 0.5f) * 0.5f -  2.f, zhi = zlo + 1.5f;

    // ---- phase 1: each wave bins its 128 gaussians (order-preserving compaction)
    int base = 0;
    #pragma unroll
    for (int r = 0; r < 2; ++r) {
        const int n = wv * 128 + r * 64 + lane;
        const float a = cov[n*9+0], bb = cov[n*9+1], c = cov[n*9+2];
        const float d = cov[n*9+4], e  = cov[n*9+5], f = cov[n*9+8];
        const float sx = sqrtf(a), sy = sqrtf(d), sz = sqrtf(f);
        const float mx = means[n*3+0], my = means[n*3+1], mz = means[n*3+2];
        const float op = opac[n];
        const bool keep =
            (mx + 3.f*sx > -20.f) && (my + 3.f*sy > -20.f) && (mz + 3.f*sz > -2.f) &&
            (mx - 3.f*sx <  20.f) && (my - 3.f*sy <  20.f) && (mz - 3.f*sz <  4.4f) &&
            (op > 1e-4f);
        const float smax = fmaxf(sx, fmaxf(sy, sz));
        const float r2 = 9.f * smax * smax;
        // distance from gaussian center to tile voxel-center AABB
        const float cx = fminf(fmaxf(mx, xlo), xhi) - mx;
        const float cy = fminf(fmaxf(my, ylo), yhi) - my;
        const float cz = fminf(fmaxf(mz, zlo), zhi) - mz;
        const float d2t = cx*cx + cy*cy + cz*cz;
        const bool pred = keep && (d2t < r2);

        const unsigned long long m = __ballot(pred);
        const int ofs = base + (int)__popcll(m & ((1ull << lane) - 1ull));
        if (pred) {
            const float det = a*(d*f - e*e) - bb*(bb*f - c*e) + c*(bb*e - c*d);
            const float id = 1.f / det;
            gd[wv][ofs][0] = make_float4(mx, my, mz, r2);
            gd[wv][ofs][1] = make_float4((d*f - e*e) * id,   // i00
                                         (c*e - bb*f) * id,  // i01
                                         (bb*e - c*d) * id,  // i02
                                         (a*f - c*c) * id);  // i11
            gd[wv][ofs][2] = make_float4((bb*c - a*e) * id,  // i12
                                         (a*d - bb*bb) * id, // i22
                                         op, 0.f);
        }
        base += (int)__popcll(m);
    }
    if (lane == 0) cnt[wv] = base;
    __syncthreads();

    // ---- phase 2: per-voxel accumulation over compacted lists (ascending n order)
    const int lz = tid & 3;
    const int ly = (tid >> 2) & 7;
    const int lx = tid >> 5;
    const int ix = tix * 8 + lx;
    const int iy = tiy * 8 + ly;
    const int iz = tiz * 4 + lz;
    const float x = (ix + 0.5f) * 0.5f - 20.f;
    const float y = (iy + 0.5f) * 0.5f - 20.f;
    const float z = (iz + 0.5f) * 0.5f -  2.f;

    float dens = 0.f;
    float4 acc[8];
    #pragma unroll
    for (int j = 0; j < 8; ++j) acc[j] = make_float4(0.f, 0.f, 0.f, 0.f);

    for (int s = 0; s < 4; ++s) {
        const int ks = cnt[s];
        for (int i = 0; i < ks; ++i) {
            const float4 p = gd[s][i][0];
            const float dx = p.x - x, dy = p.y - y, dz = p.z - z;
            const float d2 = dx*dx + dy*dy + dz*dz;
            if (d2 < p.w) {
                const float4 q = gd[s][i][1];
                const float4 t = gd[s][i][2];
                const float maha = q.x*dx*dx + q.w*dy*dy + t.y*dz*dz
                                 + 2.f*(q.y*dx*dy + q.z*dx*dz + t.x*dy*dz);
                const float w = t.z * __expf(-0.5f * maha);
                dens += w;
                // recover gaussian index for features: store it? features are keyed by n.
                // t.w carries n as float (set below) -- see phase 1 note.
                const int n = (int)t.w;
                const float4* fp = (const float4*)(feats + n * FD);
                #pragma unroll
                for (int j = 0; j < 8; ++j) {
                    const float4 f4 = fp[j];
                    acc[j].x += w * f4.x; acc[j].y += w * f4.y;
                    acc[j].z += w * f4.z; acc[j].w += w * f4.w;
                }
            }
        }
    }

    const int v = (ix * 80 + iy) * 12 + iz;
    out[v] = dens;
    const float inv = 1.f / fmaxf(dens, 1e-6f);
    float4* fo = (float4*)(out + NV + (size_t)v * FD);
    #pragma unroll
    for (int j = 0; j < 8; ++j) {
        float4 rr;
        rr.x = acc[j].x * inv; rr.y = acc[j].y * inv;
        rr.z = acc[j].z * inv; rr.w = acc[j].w * inv;
        fo[j] = rr;
    }
}

// NOTE: t.w must hold the gaussian index n. Patch phase 1 via a tiny wrapper:
// we set it directly in the stored float4 above -- replace the 0.f pad.
// (Done here by a second definition guard: the store in phase 1 uses (float)n.)
// To keep a single translation unit simple, the store above is amended below
// via macro-free duplication: see gd[wv][ofs][2] line -- it stores 0.f; we
// instead need (float)n. The actual kernel used is voxelize_kernel2.

__global__ __launch_bounds__(256) void voxelize_kernel2(
    const float* __restrict__ means, const float* __restrict__ opac,
    const float* __restrict__ cov, const float* __restrict__ feats,
    float* __restrict__ out)
{
    __shared__ float4 gd[4][128][3];
    __shared__ int cnt[4];

    const int tid  = threadIdx.x;
    const int wv   = tid >> 6;
    const int lane = tid & 63;

    const int b   = blockIdx.x;
    const int tiz = b % 3;
    const int tiy = (b / 3) % 10;
    const int tix = b / 30;

    const float xlo = (tix * 8 + 0.5f) * 0.5f - 20.f, xhi = xlo + 3.5f;
    const float ylo = (tiy * 8 + 0.5f) * 0.5f - 20.f, yhi = ylo + 3.5f;
    const float zlo = (tiz * 4 + 0.5f) * 0.5f -  2.f, zhi = zlo + 1.5f;

    int base = 0;
    #pragma unroll
    for (int r = 0; r < 2; ++r) {
        const int n = wv * 128 + r * 64 + lane;
        const float a = cov[n*9+0], bb = cov[n*9+1], c = cov[n*9+2];
        const float d = cov[n*9+4], e  = cov[n*9+5], f = cov[n*9+8];
        const float sx = sqrtf(a), sy = sqrtf(d), sz = sqrtf(f);
        const float mx = means[n*3+0], my = means[n*3+1], mz = means[n*3+2];
        const float op = opac[n];
        const bool keep =
            (mx + 3.f*sx > -20.f) && (my + 3.f*sy > -20.f) && (mz + 3.f*sz > -2.f) &&
            (mx - 3.f*sx <  20.f) && (my - 3.f*sy <  20.f) && (mz - 3.f*sz <  4.4f) &&
            (op > 1e-4f);
        const float smax = fmaxf(sx, fmaxf(sy, sz));
        const float r2 = 9.f * smax * smax;
        const float cx = fminf(fmaxf(mx, xlo), xhi) - mx;
        const float cy = fminf(fmaxf(my, ylo), yhi) - my;
        const float cz = fminf(fmaxf(mz, zlo), zhi) - mz;
        const float d2t = cx*cx + cy*cy + cz*cz;
        const bool pred = keep && (d2t < r2);

        const unsigned long long m = __ballot(pred);
        const int ofs = base + (int)__popcll(m & ((1ull << lane) - 1ull));
        if (pred) {
            const float det = a*(d*f - e*e) - bb*(bb*f - c*e) + c*(bb*e - c*d);
            const float id = 1.f / det;
            gd[wv][ofs][0] = make_float4(mx, my, mz, r2);
            gd[wv][ofs][1] = make_float4((d*f - e*e) * id,
                                         (c*e - bb*f) * id,
                                         (bb*e - c*d) * id,
                                         (a*f - c*c) * id);
            gd[wv][ofs][2] = make_float4((bb*c - a*e) * id,
                                         (a*d - bb*bb) * id,
                                         op, (float)n);
        }
        base += (int)__popcll(m);
    }
    if (lane == 0) cnt[wv] = base;
    __syncthreads();

    const int lz = tid & 3;
    const int ly = (tid >> 2) & 7;
    const int lx = tid >> 5;
    const int ix = tix * 8 + lx;
    const int iy = tiy * 8 + ly;
    const int iz = tiz * 4 + lz;
    const float x = (ix + 0.5f) * 0.5f - 20.f;
    const float y = (iy + 0.5f) * 0.5f - 20.f;
    const float z = (iz + 0.5f) * 0.5f -  2.f;

    float dens = 0.f;
    float4 acc[8];
    #pragma unroll
    for (int j = 0; j < 8; ++j) acc[j] = make_float4(0.f, 0.f, 0.f, 0.f);

    for (int s = 0; s < 4; ++s) {
        const int ks = cnt[s];
        for (int i = 0; i < ks; ++i) {
            const float4 p = gd[s][i][0];
            const float dx = p.x - x, dy = p.y - y, dz = p.z - z;
            const float d2 = dx*dx + dy*dy + dz*dz;
            if (d2 < p.w) {
                const float4 q = gd[s][i][1];
                const float4 t = gd[s][i][2];
                const float maha = q.x*dx*dx + q.w*dy*dy + t.y*dz*dz
                                 + 2.f*(q.y*dx*dy + q.z*dx*dz + t.x*dy*dz);
                const float w = t.z * __expf(-0.5f * maha);
                dens += w;
                const int n = (int)t.w;
                const float4* fp = (const float4*)(feats + n * FD);
                #pragma unroll
                for (int j = 0; j < 8; ++j) {
                    const float4 f4 = fp[j];
                    acc[j].x += w * f4.x; acc[j].y += w * f4.y;
                    acc[j].z += w * f4.z; acc[j].w += w * f4.w;
                }
            }
        }
    }

    const int v = (ix * 80 + iy) * 12 + iz;
    out[v] = dens;
    const float inv = 1.f / fmaxf(dens, 1e-6f);
    float4* fo = (float4*)(out + NV + (size_t)v * FD);
    #pragma unroll
    for (int j = 0; j < 8; ++j) {
        float4 rr;
        rr.x = acc[j].x * inv; rr.y = acc[j].y * inv;
        rr.z = acc[j].z * inv; rr.w = acc[j].w * inv;
        fo[j] = rr;
    }
}

extern "C" void kernel_launch(void* const* d_in, const int* in_sizes, int n_in,
                              void* d_out, int out_size, void* d_ws, size_t ws_size,
                              hipStream_t stream) {
    const float* means = (const float*)d_in[0];
    const float* opac  = (const float*)d_in[1];
    const float* cov   = (const float*)d_in[2];
    const float* feats = (const float*)d_in[3];
    float* out = (float*)d_out;
    voxelize_kernel2<<<300, 256, 0, stream>>>(means, opac, cov, feats, out);
}